// Round 8
// baseline (328.371 us; speedup 1.0000x reference)
//
#include <hip/hip_runtime.h>
#include <hip/hip_bf16.h>

#define P_TOTAL 160000
#define NPB     40000      // points per batch (B=4)
#define NCLS    13
#define TP      64         // points per block
#define NBLK    (P_TOTAL / TP)   // 2500

typedef __attribute__((ext_vector_type(8))) short bf16x8;    // 8 bf16 in 4 VGPRs
typedef __attribute__((ext_vector_type(4))) float f32x4;
typedef __attribute__((ext_vector_type(16))) float f32x16;   // 32x32 MFMA acc

__device__ __forceinline__ ushort f2bf(float f) {
  union { float f; unsigned u; } v; v.f = f;
  return (ushort)((v.u + 0x8000) >> 16);   // round-to-nearest (ties away)
}

// ---------------- fused prep: transposes + WT1 + histogram ----------------
// R13: frag-linear for 32x32x16 MFMA B-tiles (32 n x 16 k, 1KB each):
//   off = ((n>>5)*(K>>4) + (k>>4))*512 + (n&31)*16 + (k&15)
// Lane l of a wave reads its 16B at tile + (l&31)*16 + (l>>5)*8 (ushort units /2).
__device__ __forceinline__ void transpose_tile(const float* __restrict__ src,
                                               ushort* __restrict__ dst,
                                               int K, int N, int tile, ushort (*t)[33]) {
  int ntx = N >> 5;
  int n0 = (tile % ntx) << 5, k0 = (tile / ntx) << 5;
  int KB16 = K >> 4;
  int c = threadIdx.x & 31, r = threadIdx.x >> 5;   // 8 rows of 32
  #pragma unroll
  for (int rr = 0; rr < 32; rr += 8)
    t[r + rr][c] = f2bf(src[(k0 + r + rr) * N + n0 + c]);
  __syncthreads();
  #pragma unroll
  for (int rr = 0; rr < 32; rr += 8) {
    int n = n0 + r + rr, k = k0 + c;     // t[c][r+rr] = src[k][n]
    dst[((n >> 5) * KB16 + (k >> 4)) * 512 + (n & 31) * 16 + (k & 15)] = t[c][r + rr];
  }
}

__global__ void prep_all_kernel(const float* __restrict__ We1, const float* __restrict__ We2,
                                const float* __restrict__ W1,  const float* __restrict__ W2,
                                const int* __restrict__ y,
                                ushort* __restrict__ WT1, ushort* __restrict__ WT2,
                                ushort* __restrict__ WT3, ushort* __restrict__ WT4,
                                int* __restrict__ counts) {
  __shared__ ushort t[32][33];
  __shared__ int h[NCLS];
  int b = blockIdx.x, tid = threadIdx.x;
  if (b < 128)       transpose_tile(We2, WT2, 256, 512, b, t);
  else if (b < 256)  transpose_tile(W1,  WT3, 512, 256, b - 128, t);
  else if (b < 288)  transpose_tile(W2,  WT4, 256, 128, b - 256, t);
  else if (b == 288) {
    for (int i = tid; i < 8192; i += 256) {        // WT1: n 0..255, k 0..31 (k<7 real)
      int n = i >> 5, k = i & 31;
      WT1[((n >> 5) * 2 + (k >> 4)) * 512 + (n & 31) * 16 + (k & 15)] =
          (k < 7) ? f2bf(We1[k * 256 + n]) : (ushort)0;
    }
  } else {
    if (tid < NCLS) h[tid] = 0;
    __syncthreads();
    for (int i = (b - 289) * 256 + tid; i < P_TOTAL; i += 127 * 256)
      atomicAdd(&h[y[i]], 1);
    __syncthreads();
    if (tid < NCLS) atomicAdd(&counts[tid], h[tid]);
  }
}

// ---------------- fused MLP + norm + output + class sums + last-block finalize ----------------
// R13 (this round): all stages moved to v_mfma_f32_32x32x16_bf16.
//   Mechanism: LDS A-frag reads were the top pipe (~228 ds_read_b128/wave ~ 50% LDS
//   util); 32x32 doubles FLOP per fragment byte -> ~120 reads/wave, MFMA instrs
//   halve (146 x ~8cyc). B-loads duplicate 2x across row-halves (L2-resident, cheap).
//   Layouts: C/D col=lane&31, row=(reg&3)+8*(reg>>2)+4*(lane>>5) [m74/m101];
//   A[m=lane&31][k=(lane>>5)*8+j], B[n=lane&31][k=(lane>>5)*8+j] (mirrors the
//   verified 16x16 pattern). Wave ownership: wh=wave>>2 row-half, wq=wave&3 col-block.
//   Phase/barrier structure, LDS buffers/strides, ws layout: byte-identical to R12.
// Ledger: R4 spill; R6 LDS-diet neutral (reg-capped occupancy); R7 remap regress;
//   R9 rolled-prefetch regress; R10 setprio+LDS-atomic-csum regress; R12 frag-linear
//   B WIN 261->198us (B-gather was exposed latency).
__global__ __launch_bounds__(512, 4) void main_kernel(
    const float* __restrict__ pos, const float* __restrict__ x, const int* __restrict__ y,
    const float* __restrict__ be1, const float* __restrict__ be2,
    const float* __restrict__ b1,  const float* __restrict__ b2,
    const ushort* __restrict__ WT1, const ushort* __restrict__ WT2,
    const ushort* __restrict__ WT3, const ushort* __restrict__ WT4,
    const int* __restrict__ counts, float* __restrict__ gsums, int* __restrict__ done,
    const float* __restrict__ prior, float* __restrict__ out) {
  __shared__ ushort actbuf[TP * 264];       // 33792 B: act1 [64][256+8], later act3
  __shared__ ushort chunkbuf[TP * 136];     // 17408 B: A0 (stride 40) -> act2 chunks
                                            //   post-L3 dead -> part[4*64] f32 (1KB)
  __shared__ float  inv_norm[TP];
  __shared__ float  lbl_eff[TP];
  __shared__ int    lbl[TP];
  __shared__ float  invn[NCLS];
  __shared__ int    is_last;

  const int tid  = threadIdx.x;
  const int wave = tid >> 6, lane = tid & 63;
  const int lane31 = lane & 31, hi = lane >> 5;
  const int wh = wave >> 2, wq = wave & 3;   // row-half / col-block ownership
  const long p0 = (long)blockIdx.x * TP;     // 40000 % 64 == 0: block never spans batches
  const int bb = (int)(p0 / NPB);
  const int n0 = (int)(p0 % NPB);

  // ---- stage A0 = [x(4) | pos(3) | 0...] bf16, stride 40, into chunkbuf ----
  for (int i = tid; i < TP * 40; i += 512) {
    int r = i / 40, k = i - r * 40;
    float v = 0.f;
    if (k < 4)      v = x[(bb * 4 + k) * NPB + n0 + r];
    else if (k < 7) v = pos[(p0 + r) * 3 + (k - 4)];
    chunkbuf[r * 40 + k] = f2bf(v);
  }
  if (tid < TP) lbl[tid] = y[p0 + tid];
  __syncthreads();                                            // B1

  // ---- L1: [64x7] @ We1 -> act1[64][256]; wave tile = rows wh*32+, cols wq*64+ct*32 ----
  {
    f32x16 acc1[2];
    #pragma unroll
    for (int ct = 0; ct < 2; ct++)
      #pragma unroll
      for (int r = 0; r < 16; r++) acc1[ct][r] = 0.f;
    bf16x8 af = *(const bf16x8*)(&chunkbuf[0] + (wh * 32 + lane31) * 40 + hi * 8);
    #pragma unroll
    for (int ct = 0; ct < 2; ct++) {
      bf16x8 bw = *(const bf16x8*)(WT1 + ((wq * 2 + ct) * 2) * 512 + lane31 * 16 + hi * 8);
      acc1[ct] = __builtin_amdgcn_mfma_f32_32x32x16_bf16(af, bw, acc1[ct], 0, 0, 0);
    }
    #pragma unroll
    for (int ct = 0; ct < 2; ct++) {
      int col = wq * 64 + ct * 32 + lane31;
      float bv = be1[col];
      #pragma unroll
      for (int reg = 0; reg < 16; reg++) {
        int row = wh * 32 + (reg & 3) + 8 * (reg >> 2) + 4 * hi;
        actbuf[row * 264 + col] = f2bf(fmaxf(acc1[ct][reg] + bv, 0.f));
      }
    }
  }
  __syncthreads();                                            // B2 (also covers A0 readers)

  // ---- fused L2+L3, single chunk buffer, two barriers per chunk ----
  f32x16 acc3[2];
  #pragma unroll
  for (int ct = 0; ct < 2; ct++)
    #pragma unroll
    for (int r = 0; r < 16; r++) acc3[ct][r] = 0.f;

  ushort* const cb = &chunkbuf[0];
  for (int c = 0; c < 4; c++) {
    // L2: wave tile = rows wh*32+, chunk-local cols wq*32+ ; no cb access
    f32x16 acc2;
    #pragma unroll
    for (int r = 0; r < 16; r++) acc2[r] = 0.f;
    #pragma unroll
    for (int kt = 0; kt < 16; kt++) {
      bf16x8 af = *(const bf16x8*)(actbuf + (wh * 32 + lane31) * 264 + kt * 16 + hi * 8);
      bf16x8 bw = *(const bf16x8*)(WT2 + ((c * 4 + wq) * 16 + kt) * 512 + lane31 * 16 + hi * 8);
      acc2 = __builtin_amdgcn_mfma_f32_32x32x16_bf16(af, bw, acc2, 0, 0, 0);
    }
    if (c) __syncthreads();                                   // waves done L3(c-1) cb reads
    {
      int lc = wq * 32 + lane31;            // chunk-local col
      float bv = be2[c * 128 + lc];
      #pragma unroll
      for (int reg = 0; reg < 16; reg++) {
        int row = wh * 32 + (reg & 3) + 8 * (reg >> 2) + 4 * hi;
        cb[row * 136 + lc] = f2bf(fmaxf(acc2[reg] + bv, 0.f));
      }
    }
    __syncthreads();                                          // cb ready
    // L3: wave tile = rows wh*32+, cols wq*64+ct*32 ; accumulate this chunk's K=128
    #pragma unroll
    for (int kt = 0; kt < 8; kt++) {
      bf16x8 af = *(const bf16x8*)(cb + (wh * 32 + lane31) * 136 + kt * 16 + hi * 8);
      #pragma unroll
      for (int ct = 0; ct < 2; ct++) {
        bf16x8 bw = *(const bf16x8*)(WT3 + ((wq * 2 + ct) * 32 + c * 8 + kt) * 512 + lane31 * 16 + hi * 8);
        acc3[ct] = __builtin_amdgcn_mfma_f32_32x32x16_bf16(af, bw, acc3[ct], 0, 0, 0);
      }
    }
  }

  // ---- L3 epilogue -> act3 into actbuf (no barrier: last actbuf reads pre-B(last)) ----
  #pragma unroll
  for (int ct = 0; ct < 2; ct++) {
    int n = wq * 64 + ct * 32 + lane31;
    float bv = b1[n];
    #pragma unroll
    for (int reg = 0; reg < 16; reg++) {
      int row = wh * 32 + (reg & 3) + 8 * (reg >> 2) + 4 * hi;
      actbuf[row * 264 + n] = f2bf(fmaxf(acc3[ct][reg] + bv, 0.f));
    }
  }
  __syncthreads();                                            // B7

  // chunkbuf dead from here: alias norm partials [4 colgroups][64 rows] f32.
  float* const part = (float*)&chunkbuf[0];                   // 256 floats = 1024 B

  // ---- L4: wave tile = rows wh*32+, cols wq*32+ ; feat stays in registers ----
  f32x16 acc4;
  #pragma unroll
  for (int r = 0; r < 16; r++) acc4[r] = 0.f;
  #pragma unroll
  for (int kt = 0; kt < 16; kt++) {
    bf16x8 af = *(const bf16x8*)(actbuf + (wh * 32 + lane31) * 264 + kt * 16 + hi * 8);
    bf16x8 bw = *(const bf16x8*)(WT4 + (wq * 16 + kt) * 512 + lane31 * 16 + hi * 8);
    acc4 = __builtin_amdgcn_mfma_f32_32x32x16_bf16(af, bw, acc4, 0, 0, 0);
  }
  const int gcol = wq * 32 + lane31;
  float val[16];
  {
    float bv = b2[gcol];
    #pragma unroll
    for (int reg = 0; reg < 16; reg++) val[reg] = fmaxf(acc4[reg] + bv, 0.f);
  }

  // ---- row-norm partials: reduce each row over the wave's 32 cols (5 shfls) ----
  #pragma unroll
  for (int reg = 0; reg < 16; reg++) {
    float s = val[reg] * val[reg];
    s += __shfl_xor(s, 1);  s += __shfl_xor(s, 2);
    s += __shfl_xor(s, 4);  s += __shfl_xor(s, 8);  s += __shfl_xor(s, 16);
    if (lane31 == 0)
      part[wq * 64 + wh * 32 + (reg & 3) + 8 * (reg >> 2) + 4 * hi] = s;
  }
  __syncthreads();                                            // B8
  if (tid < TP) {
    float ss = 0.f;
    #pragma unroll
    for (int g = 0; g < 4; g++) ss += part[g * 64 + tid];
    inv_norm[tid] = 1.f / fmaxf(sqrtf(ss), 1e-12f);
    int l = lbl[tid];
    lbl_eff[tid] = (counts[l] >= 256) ? (float)l : -1.f;   // MIN_PTS gate
  }
  __syncthreads();                                            // B9

  // ---- store current_prior from regs + per-class sums (register cndmask, proven) ----
  float a[NCLS];
  #pragma unroll
  for (int cc = 0; cc < NCLS; cc++) a[cc] = 0.f;
  #pragma unroll
  for (int reg = 0; reg < 16; reg++) {
    int grow = wh * 32 + (reg & 3) + 8 * (reg >> 2) + 4 * hi;
    float vn = val[reg] * inv_norm[grow];
    out[(p0 + grow) * 129 + gcol] = vn;
    int cls = lbl[grow];
    #pragma unroll
    for (int cc = 0; cc < NCLS; cc++) a[cc] += (cls == cc) ? vn : 0.f;
  }
  if (tid < TP) out[(p0 + tid) * 129 + 128] = lbl_eff[tid];
  #pragma unroll
  for (int cc = 0; cc < NCLS; cc++) a[cc] += __shfl_xor(a[cc], 32);
  if (hi == 0)
    #pragma unroll
    for (int cc = 0; cc < NCLS; cc++) atomicAdd(&gsums[cc * 128 + gcol], a[cc]);

  // ---- last block finalizes the EMA prior (saves a dispatch) ----
  __syncthreads();                                            // B10
  if (tid == 0) {
    int old = atomicAdd(done, 1);
    is_last = (old == NBLK - 1);
  }
  __syncthreads();
  if (!is_last) return;

  float* vbuf = (float*)actbuf;            // actbuf dead; 6656 B needed
  for (int i = tid; i < NCLS * 128; i += 512) {
    float g = atomicAdd(&gsums[i], 0.f);   // coherent device-scope read
    int cls = i >> 7;
    int cnt = counts[cls];
    float mean = g / fmaxf((float)cnt, 1.f);
    float pr = prior[i];
    float cur = (cnt >= 256) ? mean : pr;
    vbuf[i] = 0.999f * pr + 0.001f * cur;
  }
  __syncthreads();
  if (tid < NCLS) {
    float s = 0.f;
    for (int c = 0; c < 128; c++) { float t = vbuf[tid * 128 + c]; s += t * t; }
    invn[tid] = 1.f / fmaxf(sqrtf(s), 1e-12f);
  }
  __syncthreads();
  for (int i = tid; i < NCLS * 128; i += 512)
    out[(long)P_TOTAL * 129 + i] = vbuf[i] * invn[i >> 7];
}

extern "C" void kernel_launch(void* const* d_in, const int* in_sizes, int n_in,
                              void* d_out, int out_size, void* d_ws, size_t ws_size,
                              hipStream_t stream) {
  const float* pos   = (const float*)d_in[0];
  const float* x     = (const float*)d_in[1];
  const int*   y     = (const int*)  d_in[2];
  const float* We1   = (const float*)d_in[3];
  const float* be1   = (const float*)d_in[4];
  const float* We2   = (const float*)d_in[5];
  const float* be2   = (const float*)d_in[6];
  const float* W1    = (const float*)d_in[7];
  const float* b1    = (const float*)d_in[8];
  const float* W2    = (const float*)d_in[9];
  const float* b2    = (const float*)d_in[10];
  const float* prior = (const float*)d_in[11];
  float* out = (float*)d_out;

  char* ws = (char*)d_ws;
  int*    counts = (int*)   (ws + 0);        //    64 B
  float*  gsums  = (float*) (ws + 256);      //  6656 B
  int*    done   = (int*)   (ws + 7168);     //     4 B
  ushort* WT1    = (ushort*)(ws + 8192);     // 16384 B  frag-linear32 [8 nb][2 kb][512]
  ushort* WT2    = (ushort*)(ws + 24576);    // 262144 B frag-linear32 [16 nb][16 kb][512]
  ushort* WT3    = (ushort*)(ws + 286720);   // 262144 B frag-linear32 [8 nb][32 kb][512]
  ushort* WT4    = (ushort*)(ws + 548864);   // 65536 B  frag-linear32 [4 nb][16 kb][512]

  hipMemsetAsync(ws, 0, 8192, stream);       // counts + gsums + done
  prep_all_kernel<<<416, 256, 0, stream>>>(We1, We2, W1, W2, y, WT1, WT2, WT3, WT4, counts);
  main_kernel    <<<NBLK, 512, 0, stream>>>(pos, x, y, be1, be2, b1, b2,
                                            WT1, WT2, WT3, WT4, counts, gsums, done, prior, out);
}

// Round 9
// 324.732 us; speedup vs baseline: 1.0112x; 1.0112x over previous
//
#include <hip/hip_runtime.h>
#include <hip/hip_bf16.h>

#define P_TOTAL 160000
#define NPB     40000      // points per batch (B=4)
#define NCLS    13
#define TP      64         // points per block
#define NBLK    (P_TOTAL / TP)   // 2500

typedef __attribute__((ext_vector_type(8))) short bf16x8;    // 8 bf16 in 4 VGPRs
typedef __attribute__((ext_vector_type(4))) float f32x4;
typedef __attribute__((ext_vector_type(16))) float f32x16;   // 32x32 MFMA acc

__device__ __forceinline__ ushort f2bf(float f) {
  union { float f; unsigned u; } v; v.f = f;
  return (ushort)((v.u + 0x8000) >> 16);   // round-to-nearest (ties away)
}

// ---------------- fused prep: transposes + WT1 + histogram ----------------
// R13 frag-linear for 32x32x16 MFMA B-tiles (32 n x 16 k, 1KB each):
//   off = ((n>>5)*(K>>4) + (k>>4))*512 + (n&31)*16 + (k&15)
// Lane l of a wave reads its 16B at tile + (l&31)*16 + (l>>5)*8 (ushort units /2).
__device__ __forceinline__ void transpose_tile(const float* __restrict__ src,
                                               ushort* __restrict__ dst,
                                               int K, int N, int tile, ushort (*t)[33]) {
  int ntx = N >> 5;
  int n0 = (tile % ntx) << 5, k0 = (tile / ntx) << 5;
  int KB16 = K >> 4;
  int c = threadIdx.x & 31, r = threadIdx.x >> 5;   // 8 rows of 32
  #pragma unroll
  for (int rr = 0; rr < 32; rr += 8)
    t[r + rr][c] = f2bf(src[(k0 + r + rr) * N + n0 + c]);
  __syncthreads();
  #pragma unroll
  for (int rr = 0; rr < 32; rr += 8) {
    int n = n0 + r + rr, k = k0 + c;     // t[c][r+rr] = src[k][n]
    dst[((n >> 5) * KB16 + (k >> 4)) * 512 + (n & 31) * 16 + (k & 15)] = t[c][r + rr];
  }
}

__global__ void prep_all_kernel(const float* __restrict__ We1, const float* __restrict__ We2,
                                const float* __restrict__ W1,  const float* __restrict__ W2,
                                const int* __restrict__ y,
                                ushort* __restrict__ WT1, ushort* __restrict__ WT2,
                                ushort* __restrict__ WT3, ushort* __restrict__ WT4,
                                int* __restrict__ counts) {
  __shared__ ushort t[32][33];
  __shared__ int h[NCLS];
  int b = blockIdx.x, tid = threadIdx.x;
  if (b < 128)       transpose_tile(We2, WT2, 256, 512, b, t);
  else if (b < 256)  transpose_tile(W1,  WT3, 512, 256, b - 128, t);
  else if (b < 288)  transpose_tile(W2,  WT4, 256, 128, b - 256, t);
  else if (b == 288) {
    for (int i = tid; i < 8192; i += 256) {        // WT1: n 0..255, k 0..31 (k<7 real)
      int n = i >> 5, k = i & 31;
      WT1[((n >> 5) * 2 + (k >> 4)) * 512 + (n & 31) * 16 + (k & 15)] =
          (k < 7) ? f2bf(We1[k * 256 + n]) : (ushort)0;
    }
  } else {
    if (tid < NCLS) h[tid] = 0;
    __syncthreads();
    for (int i = (b - 289) * 256 + tid; i < P_TOTAL; i += 127 * 256)
      atomicAdd(&h[y[i]], 1);
    __syncthreads();
    if (tid < NCLS) atomicAdd(&counts[tid], h[tid]);
  }
}

// ---------------- fused MLP + norm + output + class sums + last-block finalize ----------------
// R13 lesson (counters): 32x32 conversion halved LDS reads and ZEROED bank conflicts
//   (1.8e7 -> 352) with MFMA/VALU busy-cycles conserved — yet wall 198->267us. The
//   added time is pure stall: L2/L4 collapsed to ONE dependent MFMA chain (16 serial
//   mfma into a single acc, ~8cyc issue vs ~30cyc dep latency). L3 (ILP2) was fine.
// R14 (this round): R13 + ILP-2 accumulator split in L2 and L4 (even/odd kt chains,
//   16-add merge). Reg budget: 52 arch + 32 acc3 + 32 acc2a/b = 116 <= 128 bucket ->
//   occupancy unchanged. No layout/barrier/ownership changes vs R13.
// Ledger: R4 spill; R6 LDS-diet neutral; R7 remap regress; R9 rolled-prefetch regress;
//   R10 setprio+LDS-csum regress; R12 frag-linear B WIN 261->198; R13 32x32 ILP1
//   regress 198->267 (chain latency).
__global__ __launch_bounds__(512, 4) void main_kernel(
    const float* __restrict__ pos, const float* __restrict__ x, const int* __restrict__ y,
    const float* __restrict__ be1, const float* __restrict__ be2,
    const float* __restrict__ b1,  const float* __restrict__ b2,
    const ushort* __restrict__ WT1, const ushort* __restrict__ WT2,
    const ushort* __restrict__ WT3, const ushort* __restrict__ WT4,
    const int* __restrict__ counts, float* __restrict__ gsums, int* __restrict__ done,
    const float* __restrict__ prior, float* __restrict__ out) {
  __shared__ ushort actbuf[TP * 264];       // 33792 B: act1 [64][256+8], later act3
  __shared__ ushort chunkbuf[TP * 136];     // 17408 B: A0 (stride 40) -> act2 chunks
                                            //   post-L3 dead -> part[4*64] f32 (1KB)
  __shared__ float  inv_norm[TP];
  __shared__ float  lbl_eff[TP];
  __shared__ int    lbl[TP];
  __shared__ float  invn[NCLS];
  __shared__ int    is_last;

  const int tid  = threadIdx.x;
  const int wave = tid >> 6, lane = tid & 63;
  const int lane31 = lane & 31, hi = lane >> 5;
  const int wh = wave >> 2, wq = wave & 3;   // row-half / col-block ownership
  const long p0 = (long)blockIdx.x * TP;     // 40000 % 64 == 0: block never spans batches
  const int bb = (int)(p0 / NPB);
  const int n0 = (int)(p0 % NPB);

  // ---- stage A0 = [x(4) | pos(3) | 0...] bf16, stride 40, into chunkbuf ----
  for (int i = tid; i < TP * 40; i += 512) {
    int r = i / 40, k = i - r * 40;
    float v = 0.f;
    if (k < 4)      v = x[(bb * 4 + k) * NPB + n0 + r];
    else if (k < 7) v = pos[(p0 + r) * 3 + (k - 4)];
    chunkbuf[r * 40 + k] = f2bf(v);
  }
  if (tid < TP) lbl[tid] = y[p0 + tid];
  __syncthreads();                                            // B1

  // ---- L1: [64x7] @ We1 -> act1[64][256]; wave tile = rows wh*32+, cols wq*64+ct*32 ----
  {
    f32x16 acc1[2];
    #pragma unroll
    for (int ct = 0; ct < 2; ct++)
      #pragma unroll
      for (int r = 0; r < 16; r++) acc1[ct][r] = 0.f;
    bf16x8 af = *(const bf16x8*)(&chunkbuf[0] + (wh * 32 + lane31) * 40 + hi * 8);
    #pragma unroll
    for (int ct = 0; ct < 2; ct++) {
      bf16x8 bw = *(const bf16x8*)(WT1 + ((wq * 2 + ct) * 2) * 512 + lane31 * 16 + hi * 8);
      acc1[ct] = __builtin_amdgcn_mfma_f32_32x32x16_bf16(af, bw, acc1[ct], 0, 0, 0);
    }
    #pragma unroll
    for (int ct = 0; ct < 2; ct++) {
      int col = wq * 64 + ct * 32 + lane31;
      float bv = be1[col];
      #pragma unroll
      for (int reg = 0; reg < 16; reg++) {
        int row = wh * 32 + (reg & 3) + 8 * (reg >> 2) + 4 * hi;
        actbuf[row * 264 + col] = f2bf(fmaxf(acc1[ct][reg] + bv, 0.f));
      }
    }
  }
  __syncthreads();                                            // B2 (also covers A0 readers)

  // ---- fused L2+L3, single chunk buffer, two barriers per chunk ----
  f32x16 acc3[2];
  #pragma unroll
  for (int ct = 0; ct < 2; ct++)
    #pragma unroll
    for (int r = 0; r < 16; r++) acc3[ct][r] = 0.f;

  ushort* const cb = &chunkbuf[0];
  for (int c = 0; c < 4; c++) {
    // L2: wave tile = rows wh*32+, chunk-local cols wq*32+ ; no cb access.
    // R14: ILP-2 — even kt -> acc2a, odd kt -> acc2b, interleaved; merge after.
    f32x16 acc2a, acc2b;
    #pragma unroll
    for (int r = 0; r < 16; r++) { acc2a[r] = 0.f; acc2b[r] = 0.f; }
    #pragma unroll
    for (int kt2 = 0; kt2 < 8; kt2++) {
      bf16x8 af0 = *(const bf16x8*)(actbuf + (wh * 32 + lane31) * 264 + (2 * kt2) * 16 + hi * 8);
      bf16x8 bw0 = *(const bf16x8*)(WT2 + ((c * 4 + wq) * 16 + 2 * kt2) * 512 + lane31 * 16 + hi * 8);
      acc2a = __builtin_amdgcn_mfma_f32_32x32x16_bf16(af0, bw0, acc2a, 0, 0, 0);
      bf16x8 af1 = *(const bf16x8*)(actbuf + (wh * 32 + lane31) * 264 + (2 * kt2 + 1) * 16 + hi * 8);
      bf16x8 bw1 = *(const bf16x8*)(WT2 + ((c * 4 + wq) * 16 + 2 * kt2 + 1) * 512 + lane31 * 16 + hi * 8);
      acc2b = __builtin_amdgcn_mfma_f32_32x32x16_bf16(af1, bw1, acc2b, 0, 0, 0);
    }
    if (c) __syncthreads();                                   // waves done L3(c-1) cb reads
    {
      int lc = wq * 32 + lane31;            // chunk-local col
      float bv = be2[c * 128 + lc];
      #pragma unroll
      for (int reg = 0; reg < 16; reg++) {
        int row = wh * 32 + (reg & 3) + 8 * (reg >> 2) + 4 * hi;
        cb[row * 136 + lc] = f2bf(fmaxf(acc2a[reg] + acc2b[reg] + bv, 0.f));
      }
    }
    __syncthreads();                                          // cb ready
    // L3: wave tile = rows wh*32+, cols wq*64+ct*32 ; ILP2 via 2 ct chains (kept)
    #pragma unroll
    for (int kt = 0; kt < 8; kt++) {
      bf16x8 af = *(const bf16x8*)(cb + (wh * 32 + lane31) * 136 + kt * 16 + hi * 8);
      #pragma unroll
      for (int ct = 0; ct < 2; ct++) {
        bf16x8 bw = *(const bf16x8*)(WT3 + ((wq * 2 + ct) * 32 + c * 8 + kt) * 512 + lane31 * 16 + hi * 8);
        acc3[ct] = __builtin_amdgcn_mfma_f32_32x32x16_bf16(af, bw, acc3[ct], 0, 0, 0);
      }
    }
  }

  // ---- L3 epilogue -> act3 into actbuf (no barrier: last actbuf reads pre-B(last)) ----
  #pragma unroll
  for (int ct = 0; ct < 2; ct++) {
    int n = wq * 64 + ct * 32 + lane31;
    float bv = b1[n];
    #pragma unroll
    for (int reg = 0; reg < 16; reg++) {
      int row = wh * 32 + (reg & 3) + 8 * (reg >> 2) + 4 * hi;
      actbuf[row * 264 + n] = f2bf(fmaxf(acc3[ct][reg] + bv, 0.f));
    }
  }
  __syncthreads();                                            // B7

  // chunkbuf dead from here: alias norm partials [4 colgroups][64 rows] f32.
  float* const part = (float*)&chunkbuf[0];                   // 256 floats = 1024 B

  // ---- L4: wave tile = rows wh*32+, cols wq*32+ ; R14 ILP-2 split ----
  f32x16 acc4a, acc4b;
  #pragma unroll
  for (int r = 0; r < 16; r++) { acc4a[r] = 0.f; acc4b[r] = 0.f; }
  #pragma unroll
  for (int kt2 = 0; kt2 < 8; kt2++) {
    bf16x8 af0 = *(const bf16x8*)(actbuf + (wh * 32 + lane31) * 264 + (2 * kt2) * 16 + hi * 8);
    bf16x8 bw0 = *(const bf16x8*)(WT4 + (wq * 16 + 2 * kt2) * 512 + lane31 * 16 + hi * 8);
    acc4a = __builtin_amdgcn_mfma_f32_32x32x16_bf16(af0, bw0, acc4a, 0, 0, 0);
    bf16x8 af1 = *(const bf16x8*)(actbuf + (wh * 32 + lane31) * 264 + (2 * kt2 + 1) * 16 + hi * 8);
    bf16x8 bw1 = *(const bf16x8*)(WT4 + (wq * 16 + 2 * kt2 + 1) * 512 + lane31 * 16 + hi * 8);
    acc4b = __builtin_amdgcn_mfma_f32_32x32x16_bf16(af1, bw1, acc4b, 0, 0, 0);
  }
  const int gcol = wq * 32 + lane31;
  float val[16];
  {
    float bv = b2[gcol];
    #pragma unroll
    for (int reg = 0; reg < 16; reg++) val[reg] = fmaxf(acc4a[reg] + acc4b[reg] + bv, 0.f);
  }

  // ---- row-norm partials: reduce each row over the wave's 32 cols (5 shfls) ----
  #pragma unroll
  for (int reg = 0; reg < 16; reg++) {
    float s = val[reg] * val[reg];
    s += __shfl_xor(s, 1);  s += __shfl_xor(s, 2);
    s += __shfl_xor(s, 4);  s += __shfl_xor(s, 8);  s += __shfl_xor(s, 16);
    if (lane31 == 0)
      part[wq * 64 + wh * 32 + (reg & 3) + 8 * (reg >> 2) + 4 * hi] = s;
  }
  __syncthreads();                                            // B8
  if (tid < TP) {
    float ss = 0.f;
    #pragma unroll
    for (int g = 0; g < 4; g++) ss += part[g * 64 + tid];
    inv_norm[tid] = 1.f / fmaxf(sqrtf(ss), 1e-12f);
    int l = lbl[tid];
    lbl_eff[tid] = (counts[l] >= 256) ? (float)l : -1.f;   // MIN_PTS gate
  }
  __syncthreads();                                            // B9

  // ---- store current_prior from regs + per-class sums (register cndmask, proven) ----
  float a[NCLS];
  #pragma unroll
  for (int cc = 0; cc < NCLS; cc++) a[cc] = 0.f;
  #pragma unroll
  for (int reg = 0; reg < 16; reg++) {
    int grow = wh * 32 + (reg & 3) + 8 * (reg >> 2) + 4 * hi;
    float vn = val[reg] * inv_norm[grow];
    out[(p0 + grow) * 129 + gcol] = vn;
    int cls = lbl[grow];
    #pragma unroll
    for (int cc = 0; cc < NCLS; cc++) a[cc] += (cls == cc) ? vn : 0.f;
  }
  if (tid < TP) out[(p0 + tid) * 129 + 128] = lbl_eff[tid];
  #pragma unroll
  for (int cc = 0; cc < NCLS; cc++) a[cc] += __shfl_xor(a[cc], 32);
  if (hi == 0)
    #pragma unroll
    for (int cc = 0; cc < NCLS; cc++) atomicAdd(&gsums[cc * 128 + gcol], a[cc]);

  // ---- last block finalizes the EMA prior (saves a dispatch) ----
  __syncthreads();                                            // B10
  if (tid == 0) {
    int old = atomicAdd(done, 1);
    is_last = (old == NBLK - 1);
  }
  __syncthreads();
  if (!is_last) return;

  float* vbuf = (float*)actbuf;            // actbuf dead; 6656 B needed
  for (int i = tid; i < NCLS * 128; i += 512) {
    float g = atomicAdd(&gsums[i], 0.f);   // coherent device-scope read
    int cls = i >> 7;
    int cnt = counts[cls];
    float mean = g / fmaxf((float)cnt, 1.f);
    float pr = prior[i];
    float cur = (cnt >= 256) ? mean : pr;
    vbuf[i] = 0.999f * pr + 0.001f * cur;
  }
  __syncthreads();
  if (tid < NCLS) {
    float s = 0.f;
    for (int c = 0; c < 128; c++) { float t = vbuf[tid * 128 + c]; s += t * t; }
    invn[tid] = 1.f / fmaxf(sqrtf(s), 1e-12f);
  }
  __syncthreads();
  for (int i = tid; i < NCLS * 128; i += 512)
    out[(long)P_TOTAL * 129 + i] = vbuf[i] * invn[i >> 7];
}

extern "C" void kernel_launch(void* const* d_in, const int* in_sizes, int n_in,
                              void* d_out, int out_size, void* d_ws, size_t ws_size,
                              hipStream_t stream) {
  const float* pos   = (const float*)d_in[0];
  const float* x     = (const float*)d_in[1];
  const int*   y     = (const int*)  d_in[2];
  const float* We1   = (const float*)d_in[3];
  const float* be1   = (const float*)d_in[4];
  const float* We2   = (const float*)d_in[5];
  const float* be2   = (const float*)d_in[6];
  const float* W1    = (const float*)d_in[7];
  const float* b1    = (const float*)d_in[8];
  const float* W2    = (const float*)d_in[9];
  const float* b2    = (const float*)d_in[10];
  const float* prior = (const float*)d_in[11];
  float* out = (float*)d_out;

  char* ws = (char*)d_ws;
  int*    counts = (int*)   (ws + 0);        //    64 B
  float*  gsums  = (float*) (ws + 256);      //  6656 B
  int*    done   = (int*)   (ws + 7168);     //     4 B
  ushort* WT1    = (ushort*)(ws + 8192);     // 16384 B  frag-linear32 [8 nb][2 kb][512]
  ushort* WT2    = (ushort*)(ws + 24576);    // 262144 B frag-linear32 [16 nb][16 kb][512]
  ushort* WT3    = (ushort*)(ws + 286720);   // 262144 B frag-linear32 [8 nb][32 kb][512]
  ushort* WT4    = (ushort*)(ws + 548864);   // 65536 B  frag-linear32 [4 nb][16 kb][512]

  hipMemsetAsync(ws, 0, 8192, stream);       // counts + gsums + done
  prep_all_kernel<<<416, 256, 0, stream>>>(We1, We2, W1, W2, y, WT1, WT2, WT3, WT4, counts);
  main_kernel    <<<NBLK, 512, 0, stream>>>(pos, x, y, be1, be2, b1, b2,
                                            WT1, WT2, WT3, WT4, counts, gsums, done, prior, out);
}